// Round 9
// baseline (368.064 us; speedup 1.0000x reference)
//
#include <hip/hip_runtime.h>
#include <hip/hip_bf16.h>
#include <math.h>

// Problem constants (StructureGuidedAttention: B=4, S=1024, D=1024, H=16, dk=64, G=7)
#define BB 4
#define SS 1024
#define DD 1024
#define NH 16
#define DK 64
#define GD 7

typedef _Float16 half8 __attribute__((ext_vector_type(8)));
typedef _Float16 half4v __attribute__((ext_vector_type(4)));
typedef float floatx4 __attribute__((ext_vector_type(4)));

__device__ inline half8 cvt8(const float4 a, const float4 b) {
  half8 h;
  h[0] = (_Float16)a.x; h[1] = (_Float16)a.y; h[2] = (_Float16)a.z; h[3] = (_Float16)a.w;
  h[4] = (_Float16)b.x; h[5] = (_Float16)b.y; h[6] = (_Float16)b.z; h[7] = (_Float16)b.w;
  return h;
}

// ---------------------------------------------------------------------------
// prep: blocks 0..2047 = x fp32 -> f16; blocks 2048..3071 = pack W^T f16.
// ---------------------------------------------------------------------------
__global__ __launch_bounds__(256) void prep(const float* __restrict__ x,
                                            _Float16* __restrict__ xh,
                                            const float* __restrict__ Wq,
                                            const float* __restrict__ Wk,
                                            const float* __restrict__ Wv,
                                            const float* __restrict__ Wo,
                                            _Float16* __restrict__ Wt) {
  __shared__ _Float16 Tl[64 * 72];  // packw transpose tile [n][k], pitch 72
  const int t = threadIdx.x;
  if (blockIdx.x < 2048) {  // ---- cvtx ----
    const int i = blockIdx.x * 256 + t;
    const float4 a = ((const float4*)x)[i * 2];
    const float4 b = ((const float4*)x)[i * 2 + 1];
    ((half8*)xh)[i] = cvt8(a, b);
    return;
  }
  // ---- packw: 64x64 LDS tile transpose ----
  const int pf = blockIdx.x - 2048;
  const int z = pf >> 8, rem = pf & 255;
  const int n0 = (rem >> 4) * 64, k0 = (rem & 15) * 64;
  const float* src = (z == 0) ? Wq : (z == 1) ? Wk : (z == 2) ? Wv : Wo;
#pragma unroll
  for (int i = 0; i < 4; ++i) {
    const int u = i * 256 + t;
    const int r = u >> 4, c4 = (u & 15) * 4;
    const float4 v = *(const float4*)(src + (size_t)(k0 + r) * DD + n0 + c4);
    Tl[(c4 + 0) * 72 + r] = (_Float16)v.x;
    Tl[(c4 + 1) * 72 + r] = (_Float16)v.y;
    Tl[(c4 + 2) * 72 + r] = (_Float16)v.z;
    Tl[(c4 + 3) * 72 + r] = (_Float16)v.w;
  }
  __syncthreads();
  _Float16* dst = Wt + (size_t)z * DD * DD;
#pragma unroll
  for (int i = 0; i < 2; ++i) {
    const int u = i * 256 + t;
    const int nr = u >> 3, ks = u & 7;
    const half8 hv = *(const half8*)&Tl[nr * 72 + ks * 8];
    *(half8*)(dst + (size_t)(n0 + nr) * DD + k0 + ks * 8) = hv;
  }
}

// ---------------------------------------------------------------------------
// fused0: QKV hgemm (768 vblocks) + biasprep->fp8 C-layout (1024 vblocks),
// role-interleaved 3:4 over 1792 = 7*256 blocks.
// bias8 layout: [b][h][qt][c][w][nt][lane] u32, each u32 = 4 fp8 biases for
// accumulator regs 0..3 of that lane -> attn loads bias with 4 coalesced
// global dwords per chunk, NO LDS staging. Q output pre-scaled by 0.125.
// ---------------------------------------------------------------------------
template <bool PRE>
__global__ __launch_bounds__(256) void fused0(const _Float16* __restrict__ A,
                                              const _Float16* __restrict__ Bt,
                                              const float* __restrict__ bq,
                                              const float* __restrict__ bk,
                                              const float* __restrict__ bv,
                                              _Float16* __restrict__ Oq,
                                              _Float16* __restrict__ Ok,
                                              _Float16* __restrict__ Ov,
                                              const float* __restrict__ geom,
                                              const int* __restrict__ mask,
                                              const float* __restrict__ Wg,
                                              const float* __restrict__ bg,
                                              unsigned* __restrict__ bias8) {
  const int t = threadIdx.x;
  int role, idx;
  if (PRE) {
    const int g = blockIdx.x, grp = g / 7, rem = g % 7;  // 1792 = 7*256, 768:1024 = 3:4
    if (rem < 3) { role = 0; idx = grp * 3 + rem; }
    else         { role = 1; idx = grp * 4 + rem - 3; }
  } else {
    role = 0; idx = blockIdx.x;
  }

  if (role == 0) {
    // ================= QKV GEMM =================
    __shared__ _Float16 Als[128 * 72];  // [m][k], pitch 72
    __shared__ _Float16 Bls[128 * 72];  // [n][k]
    const int w = t >> 6, lane = t & 63, quad = lane >> 4, col = lane & 15;
    const int m0 = (idx & 31) * 128, n0 = (idx >> 5) * 128;
    const int mw = (w >> 1) * 64, nw = (w & 1) * 64;
    const floatx4 zero4 = {0.f, 0.f, 0.f, 0.f};
    floatx4 acc[4][4];
#pragma unroll
    for (int i = 0; i < 4; ++i)
#pragma unroll
      for (int j = 0; j < 4; ++j) acc[i][j] = zero4;

    for (int k0 = 0; k0 < DD; k0 += 64) {
#pragma unroll
      for (int i = 0; i < 4; ++i) {
        const int u = i * 256 + t;
        const int row = u >> 3, seg = u & 7;
        const half8 hv = *(const half8*)(A + (size_t)(m0 + row) * DD + k0 + seg * 8);
        *(half8*)&Als[row * 72 + seg * 8] = hv;
      }
#pragma unroll
      for (int i = 0; i < 4; ++i) {
        const int u = i * 256 + t;
        const int row = u >> 3, seg = u & 7;
        const half8 hv = *(const half8*)(Bt + (size_t)(n0 + row) * DD + k0 + seg * 8);
        *(half8*)&Bls[row * 72 + seg * 8] = hv;
      }
      __syncthreads();
#pragma unroll
      for (int kk = 0; kk < 2; ++kk) {
        half8 af[4], bf[4];
        const int u = (quad + kk * 4) * 8;
#pragma unroll
        for (int i = 0; i < 4; ++i)
          af[i] = *(const half8*)&Als[(mw + i * 16 + col) * 72 + u];
#pragma unroll
        for (int j = 0; j < 4; ++j)
          bf[j] = *(const half8*)&Bls[(nw + j * 16 + col) * 72 + u];
#pragma unroll
        for (int i = 0; i < 4; ++i)
#pragma unroll
          for (int j = 0; j < 4; ++j)
            acc[i][j] =
                __builtin_amdgcn_mfma_f32_16x16x32_f16(af[i], bf[j], acc[i][j], 0, 0, 0);
      }
      __syncthreads();
    }

#pragma unroll
    for (int j = 0; j < 4; ++j) {
      const int n = n0 + nw + j * 16 + col;
      const int which = n >> 10, hd = n & 1023;
      const int h = hd >> 6, d = hd & 63;
      const float* bp = (which == 0) ? bq : (which == 1) ? bk : bv;
      const float bias = bp[hd];
      const float scale = (which == 0) ? 0.125f : 1.f;  // fold 1/sqrt(dk) into Q
      _Float16* ob = (which == 0) ? Oq : (which == 1) ? Ok : Ov;
#pragma unroll
      for (int i = 0; i < 4; ++i) {
#pragma unroll
        for (int reg = 0; reg < 4; ++reg) {
          const int m = m0 + mw + i * 16 + quad * 4 + reg;
          const int b = m >> 10, s = m & 1023;
          ob[(((size_t)b * NH + h) * SS + s) * DK + d] =
              (_Float16)((acc[i][j][reg] + bias) * scale);
        }
      }
    }
    return;
  }

  if constexpr (PRE) {
    // ====== biasprep: thread = (4 q-rows, 4 keys), 16 heads, C-layout fp8 ======
    __shared__ float wgL[GD * NH + NH];
    const int r = idx;                 // 0..1023
    const int b = r >> 8;              // batch
    const int rg = r & 255;            // row-group: q rows rg*4 .. rg*4+3
    const int qt = rg >> 4, wv = (rg >> 2) & 3, quad = rg & 3;
    const int k0 = t * 4;              // 4 consecutive keys
    const int c = k0 >> 6, nt = (k0 & 63) >> 4, colb = k0 & 15;
    if (t < GD * NH) wgL[t] = Wg[t];
    if (t < NH) wgL[GD * NH + t] = bg[t];

    float4 gv[28];  // 4 q-rows x (4 keys x 7 feat) = 112 floats
#pragma unroll
    for (int qr = 0; qr < 4; ++qr) {
      const float* gp = geom + (((size_t)b * SS + rg * 4 + qr) * SS + k0) * GD;
#pragma unroll
      for (int i = 0; i < 7; ++i) gv[qr * 7 + i] = *(const float4*)(gp + i * 4);
    }
    const float* gf = (const float*)gv;  // [qr*28 + e*7 + g]
    const int4 m4 = *(const int4*)(mask + b * SS + k0);
    const int mk[4] = {m4.x, m4.y, m4.z, m4.w};
    __syncthreads();

    // u32 index: (((((b*NH+h)*16+qt)*16+c)*4+wv)*4+nt)*64 + quad*16 + colb
    const size_t base0 = (size_t)(b * NH) * 262144 + (size_t)qt * 16384 +
                         (size_t)c * 1024 + (size_t)wv * 256 + (size_t)nt * 64 +
                         quad * 16 + colb;
#pragma unroll
    for (int h = 0; h < NH; ++h) {
      float wg[GD];
#pragma unroll
      for (int g = 0; g < GD; ++g) wg[g] = wgL[g * NH + h];  // broadcast reads
      const float bgh = wgL[GD * NH + h];
      unsigned u[4];
#pragma unroll
      for (int e = 0; e < 4; ++e) {  // key e
        float bi[4];
#pragma unroll
        for (int qr = 0; qr < 4; ++qr) {
          float s = bgh;
#pragma unroll
          for (int g = 0; g < GD; ++g) s = fmaf(gf[qr * 28 + e * 7 + g], wg[g], s);
          bi[qr] = mk[e] ? s : -100.f;
        }
        int wd = 0;
        wd = __builtin_amdgcn_cvt_pk_fp8_f32(bi[0], bi[1], wd, false);
        wd = __builtin_amdgcn_cvt_pk_fp8_f32(bi[2], bi[3], wd, true);
        u[e] = (unsigned)wd;
      }
      uint4 uv = {u[0], u[1], u[2], u[3]};
      *(uint4*)(bias8 + base0 + (size_t)h * 262144) = uv;
    }
  }
}

// ---------------------------------------------------------------------------
// Out-projection hgemm: C[4096][1024] = ctxh @ Wt(o)^T + bo -> fp32 d_out
// ---------------------------------------------------------------------------
__global__ __launch_bounds__(256) void hgemm1(const _Float16* __restrict__ A,
                                              const _Float16* __restrict__ Bt,
                                              const float* __restrict__ b0,
                                              float* __restrict__ Of) {
  __shared__ _Float16 Als[128 * 72];
  __shared__ _Float16 Bls[128 * 72];
  const int t = threadIdx.x;
  const int w = t >> 6, lane = t & 63, quad = lane >> 4, col = lane & 15;
  const int m0 = blockIdx.x * 128, n0 = blockIdx.y * 128;
  const int mw = (w >> 1) * 64, nw = (w & 1) * 64;
  const floatx4 zero4 = {0.f, 0.f, 0.f, 0.f};
  floatx4 acc[4][4];
#pragma unroll
  for (int i = 0; i < 4; ++i)
#pragma unroll
    for (int j = 0; j < 4; ++j) acc[i][j] = zero4;

  for (int k0 = 0; k0 < DD; k0 += 64) {
#pragma unroll
    for (int i = 0; i < 4; ++i) {
      const int u = i * 256 + t;
      const int row = u >> 3, seg = u & 7;
      const half8 hv = *(const half8*)(A + (size_t)(m0 + row) * DD + k0 + seg * 8);
      *(half8*)&Als[row * 72 + seg * 8] = hv;
    }
#pragma unroll
    for (int i = 0; i < 4; ++i) {
      const int u = i * 256 + t;
      const int row = u >> 3, seg = u & 7;
      const half8 hv = *(const half8*)(Bt + (size_t)(n0 + row) * DD + k0 + seg * 8);
      *(half8*)&Bls[row * 72 + seg * 8] = hv;
    }
    __syncthreads();
#pragma unroll
    for (int kk = 0; kk < 2; ++kk) {
      half8 af[4], bf[4];
      const int u = (quad + kk * 4) * 8;
#pragma unroll
      for (int i = 0; i < 4; ++i) af[i] = *(const half8*)&Als[(mw + i * 16 + col) * 72 + u];
#pragma unroll
      for (int j = 0; j < 4; ++j) bf[j] = *(const half8*)&Bls[(nw + j * 16 + col) * 72 + u];
#pragma unroll
      for (int i = 0; i < 4; ++i)
#pragma unroll
        for (int j = 0; j < 4; ++j)
          acc[i][j] = __builtin_amdgcn_mfma_f32_16x16x32_f16(af[i], bf[j], acc[i][j], 0, 0, 0);
    }
    __syncthreads();
  }

#pragma unroll
  for (int j = 0; j < 4; ++j) {
    const int n = n0 + nw + j * 16 + col;
    const float bias = b0[n];
#pragma unroll
    for (int i = 0; i < 4; ++i) {
#pragma unroll
      for (int reg = 0; reg < 4; ++reg) {
        const int m = m0 + mw + i * 16 + quad * 4 + reg;
        Of[(size_t)m * DD + n] = acc[i][j][reg] + bias;
      }
    }
  }
}

// ---------------------------------------------------------------------------
// MFMA flash attention, f16 Q/K/V (Q pre-scaled by 0.125), f16 ctx out.
// PREBIAS: bias8 is C-layout-packed fp8 -> 4 coalesced global dwords per
// chunk per lane, unpacked with cvt_f32_fp8 (literal selectors); no bias LDS.
// !PREBIAS: inline geom bias fallback (f16 biasLf).
// ---------------------------------------------------------------------------
template <bool PREBIAS>
__global__ __launch_bounds__(256) void attn(const _Float16* __restrict__ Q,
                                            const _Float16* __restrict__ K,
                                            const _Float16* __restrict__ V,
                                            const unsigned* __restrict__ bias8,
                                            const float* __restrict__ geom,
                                            const int* __restrict__ mask,
                                            const float* __restrict__ Wg,
                                            const float* __restrict__ bg,
                                            _Float16* __restrict__ ctxbuf) {
  __shared__ _Float16 Ks[64 * 64];      // K chunk, half8 XOR-swizzled (Q staging pre-loop)
  __shared__ _Float16 Vt[64 * 72];      // V^T chunk [dim][key], pitch 72
  __shared__ _Float16 pL[4 * 16 * 72];  // per-wave P [16 q][key], pitch 72
  __shared__ _Float16 biasLf[PREBIAS ? 8 : 64 * 72];  // fallback only
  __shared__ unsigned char mskL[PREBIAS ? 8 : SS];    // fallback only

  const int t = threadIdx.x;
  const int w = t >> 6, lane = t & 63, quad = lane >> 4, col = lane & 15;
  const int h = blockIdx.x, qt = blockIdx.y, b = blockIdx.z;
  const int q0 = qt * 64;
  const size_t bh = (size_t)b * NH + h;
  const _Float16* Qb = Q + bh * SS * DK;
  const _Float16* Kb = K + bh * SS * DK;
  const _Float16* Vb = V + bh * SS * DK;

  {  // stage Q tile into Ks, swizzled
    const int j = t >> 2, u2 = (t & 3) * 2;
    const half8 h0 = *(const half8*)(Qb + (size_t)(q0 + j) * DK + u2 * 8);
    const half8 h1 = *(const half8*)(Qb + (size_t)(q0 + j) * DK + u2 * 8 + 8);
    *(half8*)&Ks[(j * 8 + (u2 ^ (j & 7))) * 8] = h0;
    *(half8*)&Ks[(j * 8 + ((u2 + 1) ^ (j & 7))) * 8] = h1;
  }
  if constexpr (!PREBIAS) {
    const int4 m4 = *(const int4*)(mask + b * SS + t * 4);
    mskL[t * 4 + 0] = m4.x != 0;
    mskL[t * 4 + 1] = m4.y != 0;
    mskL[t * 4 + 2] = m4.z != 0;
    mskL[t * 4 + 3] = m4.w != 0;
  }
  __syncthreads();
  half8 qfrag[2];
  {
    const int qrow = w * 16 + col;
#pragma unroll
    for (int kk = 0; kk < 2; ++kk) {
      const int u = quad + kk * 4;
      qfrag[kk] = *(const half8*)&Ks[(qrow * 8 + (u ^ (qrow & 7))) * 8];
    }
  }

  float wgv[GD];
  float bgh = 0.f;
  const float* gptr = nullptr;
  if constexpr (!PREBIAS) {
#pragma unroll
    for (int g = 0; g < GD; ++g) wgv[g] = Wg[g * NH + h];
    bgh = bg[h];
    gptr = geom + (((size_t)b * SS + (q0 + (t >> 2))) * SS + (t & 3) * 16) * GD;
  }
  // C-layout bias base: u32 idx = blockbase + ((c*4+w)*4+nt)*64 + lane
  const size_t bbase = PREBIAS ? ((bh * 16 + (size_t)qt) * 16384 + (size_t)w * 256 + lane) : 0;

  const floatx4 zero4 = {0.f, 0.f, 0.f, 0.f};
  floatx4 ctx[4] = {zero4, zero4, zero4, zero4};
  float lsum[4] = {0.f, 0.f, 0.f, 0.f};
  _Float16* pW = &pL[w * 16 * 72];

  for (int c = 0; c < 16; ++c) {
    const int k0 = c * 64;

    // ---- issue bias dword loads early (independent of LDS) ----
    unsigned bw[4];
    if constexpr (PREBIAS) {
#pragma unroll
      for (int nt = 0; nt < 4; ++nt)
        bw[nt] = bias8[bbase + (size_t)c * 1024 + nt * 64];
    }

    __syncthreads();

    {  // K chunk, swizzled
      const int j = t >> 2, u2 = (t & 3) * 2;
      const half8 h0 = *(const half8*)(Kb + (size_t)(k0 + j) * DK + u2 * 8);
      const half8 h1 = *(const half8*)(Kb + (size_t)(k0 + j) * DK + u2 * 8 + 8);
      *(half8*)&Ks[(j * 8 + (u2 ^ (j & 7))) * 8] = h0;
      *(half8*)&Ks[(j * 8 + ((u2 + 1) ^ (j & 7))) * 8] = h1;
    }
    {  // V^T chunk via 4x4 register transpose
      const int kg = (t >> 4) * 4, dg = (t & 15) * 4;
      half4v f[4];
#pragma unroll
      for (int e = 0; e < 4; ++e)
        f[e] = *(const half4v*)(Vb + (size_t)(k0 + kg + e) * DK + dg);
#pragma unroll
      for (int i = 0; i < 4; ++i) {
        half4v hv = {f[0][i], f[1][i], f[2][i], f[3][i]};
        *(half4v*)&Vt[(dg + i) * 72 + kg] = hv;
      }
    }
    if constexpr (!PREBIAS) {  // inline geom bias (fallback)
      const int gq = t >> 2, gk = (t & 3) * 16;
#pragma unroll
      for (int sg = 0; sg < 4; ++sg) {
        float4 gvv[7];
#pragma unroll
        for (int i7 = 0; i7 < 7; ++i7) gvv[i7] = *(const float4*)(gptr + sg * 28 + i7 * 4);
        const float* gf = (const float*)gvv;
        half4v bv;
#pragma unroll
        for (int k2 = 0; k2 < 4; ++k2) {
          float bi = bgh;
#pragma unroll
          for (int g = 0; g < GD; ++g) bi = fmaf(gf[k2 * GD + g], wgv[g], bi);
          bv[k2] = mskL[k0 + gk + sg * 4 + k2] ? (_Float16)bi : (_Float16)(-100.f);
        }
        *(half4v*)&biasLf[gq * 72 + gk + sg * 4] = bv;
      }
      gptr += 64 * GD;
    }
    __syncthreads();

    // ---- QK^T: 8 MFMAs -> C-layout [q=quad*4+reg][key=nt*16+col] ----
    floatx4 sc[4] = {zero4, zero4, zero4, zero4};
#pragma unroll
    for (int nt = 0; nt < 4; ++nt) {
      const int key = nt * 16 + col;
#pragma unroll
      for (int kk = 0; kk < 2; ++kk) {
        const int u = quad + kk * 4;
        const half8 kf = *(const half8*)&Ks[(key * 8 + (u ^ (key & 7))) * 8];
        sc[nt] = __builtin_amdgcn_mfma_f32_16x16x32_f16(qfrag[kk], kf, sc[nt], 0, 0, 0);
      }
    }

    // ---- p = exp(s + bias); masked keys carry bias=-100 -> p==0 ----
#pragma unroll
    for (int nt = 0; nt < 4; ++nt) {
      floatx4 b4;
      if constexpr (PREBIAS) {  // literal selectors (front-end requires ICE)
        b4[0] = __builtin_amdgcn_cvt_f32_fp8((int)bw[nt], 0);
        b4[1] = __builtin_amdgcn_cvt_f32_fp8((int)bw[nt], 1);
        b4[2] = __builtin_amdgcn_cvt_f32_fp8((int)bw[nt], 2);
        b4[3] = __builtin_amdgcn_cvt_f32_fp8((int)bw[nt], 3);
      }
#pragma unroll
      for (int reg = 0; reg < 4; ++reg) {
        const int q = quad * 4 + reg;
        float bias;
        if constexpr (PREBIAS) {
          bias = b4[reg];
        } else {
          bias = (float)biasLf[(w * 16 + q) * 72 + nt * 16 + col];
        }
        const float p = __expf(sc[nt][reg] + bias);
        lsum[reg] += p;
        pW[q * 72 + nt * 16 + col] = (_Float16)p;
      }
    }

    // ---- PV: 8 MFMAs ----
#pragma unroll
    for (int kk = 0; kk < 2; ++kk) {
      const half8 pa = *(const half8*)&pW[col * 72 + quad * 8 + kk * 32];
#pragma unroll
      for (int nt = 0; nt < 4; ++nt) {
        const half8 vb = *(const half8*)&Vt[(nt * 16 + col) * 72 + quad * 8 + kk * 32];
        ctx[nt] = __builtin_amdgcn_mfma_f32_16x16x32_f16(pa, vb, ctx[nt], 0, 0, 0);
      }
    }
  }

  float inv[4];
#pragma unroll
  for (int reg = 0; reg < 4; ++reg) {
    float l = lsum[reg];
    l += __shfl_xor(l, 1, 64);
    l += __shfl_xor(l, 2, 64);
    l += __shfl_xor(l, 4, 64);
    l += __shfl_xor(l, 8, 64);
    inv[reg] = 1.f / l;
  }
#pragma unroll
  for (int nt = 0; nt < 4; ++nt) {
#pragma unroll
    for (int reg = 0; reg < 4; ++reg) {
      const int q = q0 + w * 16 + quad * 4 + reg;
      ctxbuf[((size_t)b * SS + q) * DD + h * DK + nt * 16 + col] =
          (_Float16)(ctx[nt][reg] * inv[reg]);
    }
  }
}

// ---------------------------------------------------------------------------
extern "C" void kernel_launch(void* const* d_in, const int* in_sizes, int n_in,
                              void* d_out, int out_size, void* d_ws, size_t ws_size,
                              hipStream_t stream) {
  const float* x    = (const float*)d_in[0];
  const float* geom = (const float*)d_in[1];
  const int*   mask = (const int*)d_in[2];
  const float* Wq   = (const float*)d_in[3];
  const float* bq   = (const float*)d_in[4];
  const float* Wk   = (const float*)d_in[5];
  const float* bk   = (const float*)d_in[6];
  const float* Wv   = (const float*)d_in[7];
  const float* bv   = (const float*)d_in[8];
  const float* Wo   = (const float*)d_in[9];
  const float* bo   = (const float*)d_in[10];
  const float* Wg   = (const float*)d_in[11];
  const float* bg   = (const float*)d_in[12];
  float* out = (float*)d_out;

  const size_t NEL = (size_t)BB * SS * DD;  // 4,194,304
  char* p = (char*)d_ws;
  _Float16* xh   = (_Float16*)p;            p += NEL * 2;
  _Float16* Wt   = (_Float16*)p;            p += NEL * 2;
  _Float16* Qh   = (_Float16*)p;            p += NEL * 2;
  _Float16* Kh   = (_Float16*)p;            p += NEL * 2;
  _Float16* Vh   = (_Float16*)p;            p += NEL * 2;
  _Float16* ctxh = (_Float16*)p;            p += NEL * 2;       // 48 MiB base
  unsigned* bias8 = (unsigned*)p;                               // +64 MiB (fp8)
  const size_t need = (size_t)48 * 1024 * 1024 + (size_t)BB * NH * SS * SS;
  const bool prebias = ws_size >= need;

  prep<<<3072, 256, 0, stream>>>(x, xh, Wq, Wk, Wv, Wo, Wt);

  if (prebias) {
    fused0<true><<<1792, 256, 0, stream>>>(xh, Wt, bq, bk, bv, Qh, Kh, Vh,
                                           geom, mask, Wg, bg, bias8);
    attn<true><<<dim3(NH, SS / 64, BB), 256, 0, stream>>>(Qh, Kh, Vh, bias8, geom, mask,
                                                          Wg, bg, ctxh);
  } else {
    fused0<false><<<768, 256, 0, stream>>>(xh, Wt, bq, bk, bv, Qh, Kh, Vh,
                                           geom, mask, Wg, bg, nullptr);
    attn<false><<<dim3(NH, SS / 64, BB), 256, 0, stream>>>(Qh, Kh, Vh, nullptr, geom, mask,
                                                           Wg, bg, ctxh);
  }

  hgemm1<<<dim3(32, 8), 256, 0, stream>>>(ctxh, Wt + (size_t)3 * DD * DD, bo, out);
}